// Round 16
// baseline (27.223 us; speedup 1.0000x reference)
//
#include <hip/hip_runtime.h>

#define OBS_DIM 99
#define CH      128
#define HID     256
#define BPB     16

typedef short s8v __attribute__((ext_vector_type(8)));
typedef short s4v __attribute__((ext_vector_type(4)));
typedef float f4v __attribute__((ext_vector_type(4)));

__device__ __forceinline__ float ftanh(float x) {
    const float t = __expf(2.f * x);
    return 1.f - 2.f * __builtin_amdgcn_rcpf(t + 1.f);
}

__device__ __forceinline__ unsigned short f2bf(float f) {
    union { float f; unsigned u; } v; v.f = f;
    unsigned r = (v.u + 0x7fffu + ((v.u >> 16) & 1u)) >> 16;
    return (unsigned short)r;
}

__device__ __forceinline__ float bf2f(unsigned short u) {
    union { unsigned u; float f; } v; v.u = ((unsigned)u) << 16;
    return v.f;
}

// slot->k maps: variant c (contig) and b (blocked)
__device__ __forceinline__ int kmap(int vb, int g, int j) {
    return vb ? (g * 4 + (j & 3) + 16 * (j >> 2)) : (g * 8 + j);
}

// Wbig[k][c], K=25 used (pad 32): [0..15]=W_fgn (M), [16..19]=b_fgn (AX),
// [20..23]=W_root (X), [24]=b_conv (const-1), rest 0.
__device__ __forceinline__ float wbig_val(int k, int c, const float* Wf,
                                          const float* bf, const float* Wr,
                                          const float* bc) {
    if (k < 16) return Wf[(k >> 2) * 512 + c * 4 + (k & 3)];
    if (k < 20) return bf[c * 4 + (k - 16)];
    if (k < 24) return Wr[(k - 20) * CH + c];
    if (k == 24) return bc[c];
    return 0.f;
}

// ws layout (shorts):
//  [0)      W_dense contig hi (32768)   [32768) contig lo
//  [65536)  W_dense blocked hi          [98304) blocked lo
//  [131072) Wbig contig hi (4096)       [135168) contig lo
//  [139264) Wbig blocked hi             [143360) blocked lo
//  [147456) probe data (ints): [0..63]=per-lane scatter pack, [64]=variant|gb<<4
__global__ __launch_bounds__(256) void prepack(const float* __restrict__ W,
                                               const float* __restrict__ Wf,
                                               const float* __restrict__ bf,
                                               const float* __restrict__ Wr,
                                               const float* __restrict__ bc,
                                               unsigned short* __restrict__ ws) {
    const int gid = blockIdx.x * 256 + threadIdx.x;
    if (gid < 8192) {
        const int vb = gid >> 12, g = gid & 4095;
        const int tile = g >> 6, l = g & 63;
        const int kt = tile >> 4, nt = tile & 15;
        const int h = nt * 16 + (l & 15);
        unsigned short vh[8], vl[8];
        #pragma unroll
        for (int j = 0; j < 8; ++j) {
            const int k = kt * 32 + kmap(vb, l >> 4, j);
            const float wv = W[(size_t)k * HID + h];
            vh[j] = f2bf(wv);
            vl[j] = f2bf(wv - bf2f(vh[j]));
        }
        unsigned short* dh = ws + (size_t)vb * 65536 + (size_t)g * 8;
        *reinterpret_cast<s8v*>(dh)         = *reinterpret_cast<const s8v*>(vh);
        *reinterpret_cast<s8v*>(dh + 32768) = *reinterpret_cast<const s8v*>(vl);
    } else if (gid < 9216) {
        const int g2 = gid - 8192;
        const int vb = g2 >> 9, rest = g2 & 511;
        const int nt = rest >> 6, l = rest & 63;
        const int c = nt * 16 + (l & 15);
        unsigned short vh[8], vl[8];
        #pragma unroll
        for (int j = 0; j < 8; ++j) {
            const int k = kmap(vb, l >> 4, j);
            const float wv = wbig_val(k, c, Wf, bf, Wr, bc);
            vh[j] = f2bf(wv);
            vl[j] = f2bf(wv - bf2f(vh[j]));
        }
        unsigned short* dh = ws + 131072 + (size_t)vb * 8192 + (size_t)(nt * 64 + l) * 8;
        *reinterpret_cast<s8v*>(dh)        = *reinterpret_cast<const s8v*>(vh);
        *reinterpret_cast<s8v*>(dh + 4096) = *reinterpret_cast<const s8v*>(vl);
    }

    // ---- probes: block 0, wave 0 ----
    if (blockIdx.x == 0 && threadIdx.x < 64) {
        const int lane = threadIdx.x;
        const int g = lane >> 4;
        s8v ac, ab2, lab, ones;
        #pragma unroll
        for (int j = 0; j < 8; ++j) {
            ac[j]   = (short)f2bf((float)(kmap(0, g, j) + 1));
            ab2[j]  = (short)f2bf((float)(kmap(1, g, j) + 1));
            lab[j]  = (short)f2bf((float)(lane & 15));
            ones[j] = (short)0x3F80;
        }
        const f4v z = {0.f, 0.f, 0.f, 0.f};
        const f4v dcc = __builtin_amdgcn_mfma_f32_16x16x32_bf16(ac,  ac,  z, 0, 0, 0);
        const f4v dcb = __builtin_amdgcn_mfma_f32_16x16x32_bf16(ac,  ab2, z, 0, 0, 0);
        const f4v dbc = __builtin_amdgcn_mfma_f32_16x16x32_bf16(ab2, ac,  z, 0, 0, 0);
        const float EXP = 11440.f;
        int variant = 3;
        if      (__all(dcc[0] == EXP)) variant = 0;
        else if (__all(dcb[0] == EXP)) variant = 1;
        else if (__all(dbc[0] == EXP)) variant = 2;

        const f4v rowv = __builtin_amdgcn_mfma_f32_16x16x32_bf16(lab, ones, z, 0, 0, 0);
        const f4v colv = __builtin_amdgcn_mfma_f32_16x16x32_bf16(ones, lab, z, 0, 0, 0);
        int bi[4], hx[4];
        #pragma unroll
        for (int r = 0; r < 4; ++r) {
            int bv = (int)(rowv[r] * 0.03125f + 0.5f);
            int hv = (int)(colv[r] * 0.03125f + 0.5f);
            bi[r] = bv < 0 ? 0 : (bv > 15 ? 15 : bv);
            hx[r] = hv < 0 ? 0 : (hv > 15 ? 15 : hv);
        }
        bool gb = (bi[0] >> 2 == bi[1] >> 2) && (bi[1] >> 2 == bi[2] >> 2) &&
                  (bi[2] >> 2 == bi[3] >> 2);
        gb = gb && (((1 << (bi[0] & 3)) | (1 << (bi[1] & 3)) |
                     (1 << (bi[2] & 3)) | (1 << (bi[3] & 3))) == 0xF);
        gb = gb && (hx[0] == hx[1]) && (hx[1] == hx[2]) && (hx[2] == hx[3]);
        const int pk = bi[0] | (bi[1] << 4) | (bi[2] << 8) | (bi[3] << 12)
                     | (hx[0] << 16) | (hx[1] << 20) | (hx[2] << 24) | (hx[3] << 28);
        int bip = pk & 0xFFFF;
        bool same = true;
        #pragma unroll
        for (int st = 1; st < 16; st <<= 1)
            same = same && (bip == __shfl_xor(bip, st, 64));
        unsigned mset = 1u << hx[0];
        #pragma unroll
        for (int st = 1; st < 16; st <<= 1)
            mset |= (unsigned)__shfl_xor((int)mset, st, 64);
        gb = gb && same && (mset == 0xFFFFu);
        const int gb_all = __all(gb ? 1 : 0);

        int* pr = reinterpret_cast<int*>(ws + 147456);
        pr[lane] = pk;
        if (lane == 0) pr[64] = variant | (gb_all ? 16 : 0);
    }
}

__global__ __launch_bounds__(512, 8) void gnn_main(
    const float* __restrict__ obs,
    const float* __restrict__ W_fgn,
    const float* __restrict__ b_fgn,
    const float* __restrict__ W_root,
    const float* __restrict__ b_conv,
    const float* __restrict__ attn_k,
    const float* __restrict__ W_dense,
    const unsigned short* __restrict__ wb,   // may be null
    const int* __restrict__ probe,           // may be null
    const float* __restrict__ b_dense,
    float* __restrict__ out)
{
    // LDS overlays (18,944 B):
    //  [0,10240)      feat_h[64][40], feat_l[64][40]
    //                 -> after phase 1: part[8][64] f32 @0 (2048), attnl[64] @2048
    //  [10240,18944)  lobs f32[16][96] -> lpool_h[16][136] @10240, lpool_l @14592
    //                 (safe path: poolf f32[16][136] @10240)
    __shared__ __align__(16) unsigned char smem[18944];
    auto feat_h  = reinterpret_cast<unsigned short (*)[40]>(smem);
    auto feat_l  = reinterpret_cast<unsigned short (*)[40]>(smem + 5120);
    auto part    = reinterpret_cast<float (*)[64]>(smem);          // [8][64]
    auto attnl   = reinterpret_cast<float*>(smem + 2048);
    auto lobs    = reinterpret_cast<float (*)[96]>(smem + 10240);
    auto lpool_h = reinterpret_cast<unsigned short (*)[136]>(smem + 10240);
    auto lpool_l = reinterpret_cast<unsigned short (*)[136]>(smem + 14592);
    auto poolf   = reinterpret_cast<float (*)[136]>(smem + 10240);

    const int tid  = threadIdx.x;
    const int b0   = blockIdx.x * BPB;
    const int lane = tid & 63;
    const int w    = tid >> 6;   // 0..7

    // ---- probe data ----
    int variant = 3, groupable = 0;
    int bi_r[4] = {0, 0, 0, 0}, hx_r[4] = {0, 0, 0, 0};
    if (probe) {
        const int pk   = probe[lane];
        const int meta = probe[64];
        variant   = meta & 7;
        groupable = (meta >> 4) & 1;
        #pragma unroll
        for (int r = 0; r < 4; ++r) {
            bi_r[r] = (pk >> (4 * r)) & 15;
            hx_r[r] = (pk >> (16 + 4 * r)) & 15;
        }
    }

    // ---- stage observations (16 rows x 96 cols, 3 loads/thread) ----
    for (int i = tid; i < BPB * 96; i += 512) {
        const int bi = i / 96, col = i - bi * 96;
        lobs[bi][col] = obs[(size_t)(b0 + bi) * OBS_DIM + 3 + col];
    }
    __syncthreads();

    // ---- build feat rows (hi/lo bf16) ----
    if (tid < 256) {   // M[t][e][f]
        const int bi = tid >> 4, t = (tid >> 2) & 3, e = tid & 3;
        const int row = bi * 4 + t;
        float m[4] = {0.f, 0.f, 0.f, 0.f};
        #pragma unroll
        for (int s = 0; s < 4; ++s) {
            const float ae = lobs[bi][16 + t * 4 + s] * lobs[bi][32 + (t * 4 + s) * 4 + e];
            #pragma unroll
            for (int f = 0; f < 4; ++f) m[f] = fmaf(ae, lobs[bi][s * 4 + f], m[f]);
        }
        #pragma unroll
        for (int f = 0; f < 4; ++f) {
            const unsigned short h = f2bf(m[f]);
            feat_h[row][e * 4 + f] = h;
            feat_l[row][e * 4 + f] = f2bf(m[f] - bf2f(h));
        }
    } else if (tid < 320) {   // AX -> k=16..19
        const int q = tid - 256;
        const int bi = q >> 2, t = q & 3, row = bi * 4 + t;
        #pragma unroll
        for (int f = 0; f < 4; ++f) {
            float ax = 0.f;
            #pragma unroll
            for (int s = 0; s < 4; ++s)
                ax = fmaf(lobs[bi][16 + t * 4 + s], lobs[bi][s * 4 + f], ax);
            const unsigned short h = f2bf(ax);
            feat_h[row][16 + f] = h;
            feat_l[row][16 + f] = f2bf(ax - bf2f(h));
        }
    } else if (tid < 384) {   // X (20..23), 1 (24), zeros (25..31)
        const int q = tid - 320;
        const int bi = q >> 2, t = q & 3, row = bi * 4 + t;
        #pragma unroll
        for (int f = 0; f < 4; ++f) {
            const float xv = lobs[bi][t * 4 + f];
            const unsigned short h = f2bf(xv);
            feat_h[row][20 + f] = h;
            feat_l[row][20 + f] = f2bf(xv - bf2f(h));
        }
        feat_h[row][24] = 0x3F80; feat_l[row][24] = 0;
        #pragma unroll
        for (int k = 25; k < 32; ++k) { feat_h[row][k] = 0; feat_l[row][k] = 0; }
    }
    __syncthreads();

    if (variant < 3 && groupable) {
        // ================= FAST PATH =================
        const int hx0 = hx_r[0];
        const int ib  = bi_r[0] >> 2;

        // phase 1: wave w owns 16-col slice [16w, 16w+16)
        const s8v* B1h = reinterpret_cast<const s8v*>(wb + 131072 + (variant == 1 ? 8192 : 0));
        const s8v* B1l = B1h + 512;
        const s8v bh1 = B1h[w * 64 + lane];
        const s8v bl1 = B1l[w * 64 + lane];
        const float akv = attn_k[w * 16 + hx0];

        float xc[4][4];
        float part16[16];

        #pragma unroll
        for (int rt = 0; rt < 4; ++rt) {
            const int row = rt * 16 + (lane & 15);
            s8v ah, al;
            if (variant != 2) {
                ah = *reinterpret_cast<const s8v*>(&feat_h[row][(lane >> 4) * 8]);
                al = *reinterpret_cast<const s8v*>(&feat_l[row][(lane >> 4) * 8]);
            } else {
                const s4v h0 = *reinterpret_cast<const s4v*>(&feat_h[row][(lane >> 4) * 4]);
                const s4v h1 = *reinterpret_cast<const s4v*>(&feat_h[row][16 + (lane >> 4) * 4]);
                const s4v l0 = *reinterpret_cast<const s4v*>(&feat_l[row][(lane >> 4) * 4]);
                const s4v l1 = *reinterpret_cast<const s4v*>(&feat_l[row][16 + (lane >> 4) * 4]);
                ah = __builtin_shufflevector(h0, h1, 0, 1, 2, 3, 4, 5, 6, 7);
                al = __builtin_shufflevector(l0, l1, 0, 1, 2, 3, 4, 5, 6, 7);
            }
            f4v acc = {0.f, 0.f, 0.f, 0.f};
            acc = __builtin_amdgcn_mfma_f32_16x16x32_bf16(al, bh1, acc, 0, 0, 0);
            acc = __builtin_amdgcn_mfma_f32_16x16x32_bf16(ah, bl1, acc, 0, 0, 0);
            acc = __builtin_amdgcn_mfma_f32_16x16x32_bf16(ah, bh1, acc, 0, 0, 0);
            #pragma unroll
            for (int r = 0; r < 4; ++r) {
                const float v = fmaxf(acc[r], 0.f);
                xc[rt][r] = v;
                part16[rt * 4 + r] = v * akv;
            }
        }

        // intra-16-lane logit reduce (cols of this wave's slice)
        #pragma unroll
        for (int st = 1; st < 16; st <<= 1) {
            #pragma unroll
            for (int i = 0; i < 16; ++i)
                part16[i] += __shfl_xor(part16[i], st, 64);
        }
        __syncthreads();   // feat dead; part overlays feat
        if ((lane & 15) == 0) {
            #pragma unroll
            for (int rt = 0; rt < 4; ++rt)
                #pragma unroll
                for (int r = 0; r < 4; ++r)
                    part[w][rt * 16 + bi_r[r]] = part16[rt * 4 + r];
        }
        __syncthreads();

        // softmax over t within each item
        if (tid < 64) {
            float l = 0.f;
            #pragma unroll
            for (int q = 0; q < 8; ++q) l += part[q][tid];
            float m1 = fmaxf(l, __shfl_xor(l, 1, 64));
            m1 = fmaxf(m1, __shfl_xor(m1, 2, 64));
            const float e = __expf(l - m1);
            float s = e + __shfl_xor(e, 1, 64);
            s += __shfl_xor(s, 2, 64);
            attnl[tid] = e * __builtin_amdgcn_rcpf(s);
        }
        __syncthreads();

        // pooling: thread-local; col = w*16 + hx0
        #pragma unroll
        for (int rt = 0; rt < 4; ++rt) {
            float p = 0.f;
            #pragma unroll
            for (int r = 0; r < 4; ++r)
                p = fmaf(attnl[rt * 16 + bi_r[r]], xc[rt][r], p);
            const int item = rt * 4 + ib;
            const int c = w * 16 + hx0;
            const unsigned short h = f2bf(p);
            lpool_h[item][c] = h;
            lpool_l[item][c] = f2bf(p - bf2f(h));
        }
        __syncthreads();

        // phase 2: wave w owns cols [32w, 32w+32) = 2 nt tiles
        const s8v* Bh = reinterpret_cast<const s8v*>(wb + (variant == 1 ? 65536 : 0));
        const s8v* Bl = reinterpret_cast<const s8v*>(wb + (variant == 1 ? 98304 : 32768));
        f4v acc2[2] = {f4v{0,0,0,0}, f4v{0,0,0,0}};
        #pragma unroll 1
        for (int ks = 0; ks < 4; ++ks) {
            s8v ah, al;
            if (variant != 2) {
                ah = *reinterpret_cast<const s8v*>(&lpool_h[lane & 15][ks * 32 + (lane >> 4) * 8]);
                al = *reinterpret_cast<const s8v*>(&lpool_l[lane & 15][ks * 32 + (lane >> 4) * 8]);
            } else {
                const s4v h0 = *reinterpret_cast<const s4v*>(&lpool_h[lane & 15][ks * 32 + (lane >> 4) * 4]);
                const s4v h1 = *reinterpret_cast<const s4v*>(&lpool_h[lane & 15][ks * 32 + 16 + (lane >> 4) * 4]);
                const s4v l0 = *reinterpret_cast<const s4v*>(&lpool_l[lane & 15][ks * 32 + (lane >> 4) * 4]);
                const s4v l1 = *reinterpret_cast<const s4v*>(&lpool_l[lane & 15][ks * 32 + 16 + (lane >> 4) * 4]);
                ah = __builtin_shufflevector(h0, h1, 0, 1, 2, 3, 4, 5, 6, 7);
                al = __builtin_shufflevector(l0, l1, 0, 1, 2, 3, 4, 5, 6, 7);
            }
            #pragma unroll
            for (int ntl = 0; ntl < 2; ++ntl) {
                const int idx = (ks * 16 + (w * 2 + ntl)) * 64 + lane;
                const s8v bh = Bh[idx], bl = Bl[idx];
                acc2[ntl] = __builtin_amdgcn_mfma_f32_16x16x32_bf16(al, bh, acc2[ntl], 0, 0, 0);
                acc2[ntl] = __builtin_amdgcn_mfma_f32_16x16x32_bf16(ah, bl, acc2[ntl], 0, 0, 0);
                acc2[ntl] = __builtin_amdgcn_mfma_f32_16x16x32_bf16(ah, bh, acc2[ntl], 0, 0, 0);
            }
        }
        #pragma unroll
        for (int ntl = 0; ntl < 2; ++ntl) {
            #pragma unroll
            for (int r = 0; r < 4; ++r) {
                const int h = (w * 2 + ntl) * 16 + hx_r[r];
                out[(size_t)(b0 + bi_r[r]) * HID + h] = ftanh(acc2[ntl][r] + b_dense[h]);
            }
        }
    } else {
        // ================= SAFE PATH (fp32; waves 0..3 active) =================
        if (w < 4) {
            #pragma unroll 1
            for (int p = 0; p < 4; ++p) {
                const int item = w * 4 + p;
                float xc2[2][4], pt[4] = {0.f, 0.f, 0.f, 0.f};
                #pragma unroll 1
                for (int ch = 0; ch < 2; ++ch) {
                    const int cc = lane + ch * 64;
                    #pragma unroll
                    for (int t = 0; t < 4; ++t) {
                        const int row = item * 4 + t;
                        float v = 0.f;
                        #pragma unroll 5
                        for (int k = 0; k < 25; ++k) {
                            const float fv = bf2f(feat_h[row][k]) + bf2f(feat_l[row][k]);
                            v = fmaf(fv, wbig_val(k, cc, W_fgn, b_fgn, W_root, b_conv), v);
                        }
                        xc2[ch][t] = fmaxf(v, 0.f);
                        pt[t] = fmaf(xc2[ch][t], attn_k[cc], pt[t]);
                    }
                }
                #pragma unroll
                for (int st = 1; st < 64; st <<= 1) {
                    #pragma unroll
                    for (int t = 0; t < 4; ++t) pt[t] += __shfl_xor(pt[t], st, 64);
                }
                const float mx = fmaxf(fmaxf(pt[0], pt[1]), fmaxf(pt[2], pt[3]));
                const float e0 = __expf(pt[0] - mx), e1 = __expf(pt[1] - mx);
                const float e2 = __expf(pt[2] - mx), e3 = __expf(pt[3] - mx);
                const float inv = 1.f / (e0 + e1 + e2 + e3);
                poolf[item][lane]      = (e0 * xc2[0][0] + e1 * xc2[0][1] + e2 * xc2[0][2] + e3 * xc2[0][3]) * inv;
                poolf[item][lane + 64] = (e0 * xc2[1][0] + e1 * xc2[1][1] + e2 * xc2[1][2] + e3 * xc2[1][3]) * inv;
            }
        }
        __syncthreads();

        if (w < 4) {
            const int col0 = w * 64 + (lane & 15) * 4;
            const int rb   = (lane >> 4) * 4;
            float acc[4][4];
            #pragma unroll
            for (int j = 0; j < 4; ++j)
                #pragma unroll
                for (int i = 0; i < 4; ++i) acc[j][i] = 0.f;
            #pragma unroll 4
            for (int cc = 0; cc < CH; cc += 4) {
                float4 pv[4], wr[4];
                #pragma unroll
                for (int j = 0; j < 4; ++j) {
                    pv[j].x = poolf[rb + j][cc];     pv[j].y = poolf[rb + j][cc + 1];
                    pv[j].z = poolf[rb + j][cc + 2]; pv[j].w = poolf[rb + j][cc + 3];
                }
                #pragma unroll
                for (int k = 0; k < 4; ++k)
                    wr[k] = *reinterpret_cast<const float4*>(&W_dense[(size_t)(cc + k) * HID + col0]);
                #pragma unroll
                for (int j = 0; j < 4; ++j) {
                    const float pj[4] = {pv[j].x, pv[j].y, pv[j].z, pv[j].w};
                    #pragma unroll
                    for (int k = 0; k < 4; ++k) {
                        acc[j][0] = fmaf(pj[k], wr[k].x, acc[j][0]);
                        acc[j][1] = fmaf(pj[k], wr[k].y, acc[j][1]);
                        acc[j][2] = fmaf(pj[k], wr[k].z, acc[j][2]);
                        acc[j][3] = fmaf(pj[k], wr[k].w, acc[j][3]);
                    }
                }
            }
            const float4 bd = *reinterpret_cast<const float4*>(&b_dense[col0]);
            #pragma unroll
            for (int j = 0; j < 4; ++j) {
                float4 o;
                o.x = ftanh(acc[j][0] + bd.x);
                o.y = ftanh(acc[j][1] + bd.y);
                o.z = ftanh(acc[j][2] + bd.z);
                o.w = ftanh(acc[j][3] + bd.w);
                *reinterpret_cast<float4*>(&out[(size_t)(b0 + rb + j) * HID + col0]) = o;
            }
        }
    }
}

extern "C" void kernel_launch(void* const* d_in, const int* in_sizes, int n_in,
                              void* d_out, int out_size, void* d_ws, size_t ws_size,
                              hipStream_t stream) {
    const float* obs     = (const float*)d_in[0];
    const float* W_fgn   = (const float*)d_in[1];
    const float* b_fgn   = (const float*)d_in[2];
    const float* W_root  = (const float*)d_in[3];
    const float* b_conv  = (const float*)d_in[4];
    const float* attn_k  = (const float*)d_in[5];
    const float* W_dense = (const float*)d_in[6];
    const float* b_dense = (const float*)d_in[7];
    float* out = (float*)d_out;

    const int Bn = in_sizes[0] / OBS_DIM;     // 16384
    const bool use_ws = (ws_size >= 320 * 1024) && (d_ws != nullptr);

    if (use_ws) {
        unsigned short* wb = (unsigned short*)d_ws;
        prepack<<<36, 256, 0, stream>>>(W_dense, W_fgn, b_fgn, W_root, b_conv, wb);
        gnn_main<<<Bn / BPB, 512, 0, stream>>>(obs, W_fgn, b_fgn, W_root, b_conv,
                                               attn_k, W_dense, wb,
                                               (const int*)(wb + 147456), b_dense, out);
    } else {
        gnn_main<<<Bn / BPB, 512, 0, stream>>>(obs, W_fgn, b_fgn, W_root, b_conv,
                                               attn_k, W_dense, nullptr, nullptr,
                                               b_dense, out);
    }
}

// Round 18
// 23.720 us; speedup vs baseline: 1.1477x; 1.1477x over previous
//
#include <hip/hip_runtime.h>

#define OBS_DIM 99
#define CH      128
#define HID     256
#define BPB     16

typedef short s8v __attribute__((ext_vector_type(8)));
typedef short s4v __attribute__((ext_vector_type(4)));
typedef float f4v __attribute__((ext_vector_type(4)));

__device__ __forceinline__ float ftanh(float x) {
    const float t = __expf(2.f * x);
    return 1.f - 2.f * __builtin_amdgcn_rcpf(t + 1.f);
}

__device__ __forceinline__ unsigned short f2bf(float f) {
    union { float f; unsigned u; } v; v.f = f;
    unsigned r = (v.u + 0x7fffu + ((v.u >> 16) & 1u)) >> 16;
    return (unsigned short)r;
}

__device__ __forceinline__ float bf2f(unsigned short u) {
    union { unsigned u; float f; } v; v.u = ((unsigned)u) << 16;
    return v.f;
}

// slot->k maps: variant c (contig) and b (blocked)
__device__ __forceinline__ int kmap(int vb, int g, int j) {
    return vb ? (g * 4 + (j & 3) + 16 * (j >> 2)) : (g * 8 + j);
}

// Wbig[k][c], K=25 used (pad 32): [0..15]=W_fgn (M), [16..19]=b_fgn (AX),
// [20..23]=W_root (X), [24]=b_conv (const-1), rest 0.
__device__ __forceinline__ float wbig_val(int k, int c, const float* Wf,
                                          const float* bf, const float* Wr,
                                          const float* bc) {
    if (k < 16) return Wf[(k >> 2) * 512 + c * 4 + (k & 3)];
    if (k < 20) return bf[c * 4 + (k - 16)];
    if (k < 24) return Wr[(k - 20) * CH + c];
    if (k == 24) return bc[c];
    return 0.f;
}

// ws layout (shorts):
//  [0)      W_dense contig hi (32768)   [32768) contig lo
//  [65536)  W_dense blocked hi          [98304) blocked lo
//  [131072) Wbig contig hi (4096)       [135168) contig lo
//  [139264) Wbig blocked hi             [143360) blocked lo
//  [147456) probe data (ints): [0..63]=per-lane scatter pack, [64]=variant|gb<<4
__global__ __launch_bounds__(256) void prepack(const float* __restrict__ W,
                                               const float* __restrict__ Wf,
                                               const float* __restrict__ bf,
                                               const float* __restrict__ Wr,
                                               const float* __restrict__ bc,
                                               unsigned short* __restrict__ ws) {
    const int gid = blockIdx.x * 256 + threadIdx.x;
    if (gid < 8192) {
        const int vb = gid >> 12, g = gid & 4095;
        const int tile = g >> 6, l = g & 63;
        const int kt = tile >> 4, nt = tile & 15;
        const int h = nt * 16 + (l & 15);
        unsigned short vh[8], vl[8];
        #pragma unroll
        for (int j = 0; j < 8; ++j) {
            const int k = kt * 32 + kmap(vb, l >> 4, j);
            const float wv = W[(size_t)k * HID + h];
            vh[j] = f2bf(wv);
            vl[j] = f2bf(wv - bf2f(vh[j]));
        }
        unsigned short* dh = ws + (size_t)vb * 65536 + (size_t)g * 8;
        *reinterpret_cast<s8v*>(dh)         = *reinterpret_cast<const s8v*>(vh);
        *reinterpret_cast<s8v*>(dh + 32768) = *reinterpret_cast<const s8v*>(vl);
    } else if (gid < 9216) {
        const int g2 = gid - 8192;
        const int vb = g2 >> 9, rest = g2 & 511;
        const int nt = rest >> 6, l = rest & 63;
        const int c = nt * 16 + (l & 15);
        unsigned short vh[8], vl[8];
        #pragma unroll
        for (int j = 0; j < 8; ++j) {
            const int k = kmap(vb, l >> 4, j);
            const float wv = wbig_val(k, c, Wf, bf, Wr, bc);
            vh[j] = f2bf(wv);
            vl[j] = f2bf(wv - bf2f(vh[j]));
        }
        unsigned short* dh = ws + 131072 + (size_t)vb * 8192 + (size_t)(nt * 64 + l) * 8;
        *reinterpret_cast<s8v*>(dh)        = *reinterpret_cast<const s8v*>(vh);
        *reinterpret_cast<s8v*>(dh + 4096) = *reinterpret_cast<const s8v*>(vl);
    }

    // ---- probes: block 0, wave 0 ----
    if (blockIdx.x == 0 && threadIdx.x < 64) {
        const int lane = threadIdx.x;
        const int g = lane >> 4;
        s8v ac, ab2, lab, ones;
        #pragma unroll
        for (int j = 0; j < 8; ++j) {
            ac[j]   = (short)f2bf((float)(kmap(0, g, j) + 1));
            ab2[j]  = (short)f2bf((float)(kmap(1, g, j) + 1));
            lab[j]  = (short)f2bf((float)(lane & 15));
            ones[j] = (short)0x3F80;
        }
        const f4v z = {0.f, 0.f, 0.f, 0.f};
        const f4v dcc = __builtin_amdgcn_mfma_f32_16x16x32_bf16(ac,  ac,  z, 0, 0, 0);
        const f4v dcb = __builtin_amdgcn_mfma_f32_16x16x32_bf16(ac,  ab2, z, 0, 0, 0);
        const f4v dbc = __builtin_amdgcn_mfma_f32_16x16x32_bf16(ab2, ac,  z, 0, 0, 0);
        const float EXP = 11440.f;
        int variant = 3;
        if      (__all(dcc[0] == EXP)) variant = 0;
        else if (__all(dcb[0] == EXP)) variant = 1;
        else if (__all(dbc[0] == EXP)) variant = 2;

        const f4v rowv = __builtin_amdgcn_mfma_f32_16x16x32_bf16(lab, ones, z, 0, 0, 0);
        const f4v colv = __builtin_amdgcn_mfma_f32_16x16x32_bf16(ones, lab, z, 0, 0, 0);
        int bi[4], hx[4];
        #pragma unroll
        for (int r = 0; r < 4; ++r) {
            int bv = (int)(rowv[r] * 0.03125f + 0.5f);
            int hv = (int)(colv[r] * 0.03125f + 0.5f);
            bi[r] = bv < 0 ? 0 : (bv > 15 ? 15 : bv);
            hx[r] = hv < 0 ? 0 : (hv > 15 ? 15 : hv);
        }
        bool gb = (bi[0] >> 2 == bi[1] >> 2) && (bi[1] >> 2 == bi[2] >> 2) &&
                  (bi[2] >> 2 == bi[3] >> 2);
        gb = gb && (((1 << (bi[0] & 3)) | (1 << (bi[1] & 3)) |
                     (1 << (bi[2] & 3)) | (1 << (bi[3] & 3))) == 0xF);
        gb = gb && (hx[0] == hx[1]) && (hx[1] == hx[2]) && (hx[2] == hx[3]);
        const int pk = bi[0] | (bi[1] << 4) | (bi[2] << 8) | (bi[3] << 12)
                     | (hx[0] << 16) | (hx[1] << 20) | (hx[2] << 24) | (hx[3] << 28);
        int bip = pk & 0xFFFF;
        bool same = true;
        #pragma unroll
        for (int st = 1; st < 16; st <<= 1)
            same = same && (bip == __shfl_xor(bip, st, 64));
        unsigned mset = 1u << hx[0];
        #pragma unroll
        for (int st = 1; st < 16; st <<= 1)
            mset |= (unsigned)__shfl_xor((int)mset, st, 64);
        gb = gb && same && (mset == 0xFFFFu);
        const int gb_all = __all(gb ? 1 : 0);

        int* pr = reinterpret_cast<int*>(ws + 147456);
        pr[lane] = pk;
        if (lane == 0) pr[64] = variant | (gb_all ? 16 : 0);
    }
}

__global__ __launch_bounds__(256, 4) void gnn_main(
    const float* __restrict__ obs,
    const float* __restrict__ W_fgn,
    const float* __restrict__ b_fgn,
    const float* __restrict__ W_root,
    const float* __restrict__ b_conv,
    const float* __restrict__ attn_k,
    const float* __restrict__ W_dense,
    const unsigned short* __restrict__ wb,   // may be null
    const int* __restrict__ probe,           // may be null
    const float* __restrict__ b_dense,
    float* __restrict__ out)
{
    // LDS overlays (18,944 B):
    //  [0,10240)      feat_h[64][40], feat_l[64][40]
    //                 -> after phase 1: part[4][64] @0, attnl[64] @1024
    //  [10240,18944)  lobs f32[16][96] -> lpool_h[16][136] @10240, lpool_l @14592
    //                 (safe path: poolf f32[16][136] @10240)
    __shared__ __align__(16) unsigned char smem[18944];
    auto feat_h  = reinterpret_cast<unsigned short (*)[40]>(smem);
    auto feat_l  = reinterpret_cast<unsigned short (*)[40]>(smem + 5120);
    auto part    = reinterpret_cast<float (*)[64]>(smem);
    auto attnl   = reinterpret_cast<float*>(smem + 1024);
    auto lobs    = reinterpret_cast<float (*)[96]>(smem + 10240);
    auto lpool_h = reinterpret_cast<unsigned short (*)[136]>(smem + 10240);
    auto lpool_l = reinterpret_cast<unsigned short (*)[136]>(smem + 14592);
    auto poolf   = reinterpret_cast<float (*)[136]>(smem + 10240);

    const int tid  = threadIdx.x;
    const int b0   = blockIdx.x * BPB;
    const int lane = tid & 63;
    const int w    = tid >> 6;

    // ---- probe data ----
    int variant = 3, groupable = 0;
    int bi_r[4] = {0, 0, 0, 0}, hx_r[4] = {0, 0, 0, 0};
    if (probe) {
        const int pk   = probe[lane];
        const int meta = probe[64];
        variant   = meta & 7;
        groupable = (meta >> 4) & 1;
        #pragma unroll
        for (int r = 0; r < 4; ++r) {
            bi_r[r] = (pk >> (4 * r)) & 15;
            hx_r[r] = (pk >> (16 + 4 * r)) & 15;
        }
    }

    // ---- stage observations ----
    for (int i = tid; i < BPB * 96; i += 256) {
        const int bi = i / 96, col = i - bi * 96;
        lobs[bi][col] = obs[(size_t)(b0 + bi) * OBS_DIM + 3 + col];
    }
    __syncthreads();

    // ---- build feat rows (hi/lo bf16) ----
    {   // M[t][e][f]
        const int bi = tid >> 4, t = (tid >> 2) & 3, e = tid & 3;
        const int row = bi * 4 + t;
        float m[4] = {0.f, 0.f, 0.f, 0.f};
        #pragma unroll
        for (int s = 0; s < 4; ++s) {
            const float ae = lobs[bi][16 + t * 4 + s] * lobs[bi][32 + (t * 4 + s) * 4 + e];
            #pragma unroll
            for (int f = 0; f < 4; ++f) m[f] = fmaf(ae, lobs[bi][s * 4 + f], m[f]);
        }
        #pragma unroll
        for (int f = 0; f < 4; ++f) {
            const unsigned short h = f2bf(m[f]);
            feat_h[row][e * 4 + f] = h;
            feat_l[row][e * 4 + f] = f2bf(m[f] - bf2f(h));
        }
    }
    if (tid < 64) {   // AX -> k=16..19
        const int bi = tid >> 2, t = tid & 3, row = bi * 4 + t;
        #pragma unroll
        for (int f = 0; f < 4; ++f) {
            float ax = 0.f;
            #pragma unroll
            for (int s = 0; s < 4; ++s)
                ax = fmaf(lobs[bi][16 + t * 4 + s], lobs[bi][s * 4 + f], ax);
            const unsigned short h = f2bf(ax);
            feat_h[row][16 + f] = h;
            feat_l[row][16 + f] = f2bf(ax - bf2f(h));
        }
    } else if (tid < 128) {   // X (20..23), 1 (24), zeros (25..31)
        const int q = tid - 64;
        const int bi = q >> 2, t = q & 3, row = bi * 4 + t;
        #pragma unroll
        for (int f = 0; f < 4; ++f) {
            const float xv = lobs[bi][t * 4 + f];
            const unsigned short h = f2bf(xv);
            feat_h[row][20 + f] = h;
            feat_l[row][20 + f] = f2bf(xv - bf2f(h));
        }
        feat_h[row][24] = 0x3F80; feat_l[row][24] = 0;
        #pragma unroll
        for (int k = 25; k < 32; ++k) { feat_h[row][k] = 0; feat_l[row][k] = 0; }
    }
    __syncthreads();

    if (variant < 3 && groupable) {
        // ================= FAST PATH (all-MFMA, xc in registers) =================
        const int hx0 = hx_r[0];
        const int ib  = bi_r[0] >> 2;

        // phase 1: xc = relu(feat @ Wbig)
        const s8v* B1h = reinterpret_cast<const s8v*>(wb + 131072 + (variant == 1 ? 8192 : 0));
        const s8v* B1l = B1h + 512;
        s8v bh1[2], bl1[2];
        float akv[2];
        #pragma unroll
        for (int ctl = 0; ctl < 2; ++ctl) {
            const int idx = (w * 2 + ctl) * 64 + lane;
            bh1[ctl] = B1h[idx]; bl1[ctl] = B1l[idx];
            akv[ctl] = attn_k[w * 32 + ctl * 16 + hx0];
        }

        float xc[4][2][4];
        float v[16];
        #pragma unroll
        for (int i = 0; i < 16; ++i) v[i] = 0.f;

        #pragma unroll
        for (int rt = 0; rt < 4; ++rt) {
            const int row = rt * 16 + (lane & 15);
            s8v ah, al;
            if (variant != 2) {
                ah = *reinterpret_cast<const s8v*>(&feat_h[row][(lane >> 4) * 8]);
                al = *reinterpret_cast<const s8v*>(&feat_l[row][(lane >> 4) * 8]);
            } else {
                const s4v h0 = *reinterpret_cast<const s4v*>(&feat_h[row][(lane >> 4) * 4]);
                const s4v h1 = *reinterpret_cast<const s4v*>(&feat_h[row][16 + (lane >> 4) * 4]);
                const s4v l0 = *reinterpret_cast<const s4v*>(&feat_l[row][(lane >> 4) * 4]);
                const s4v l1 = *reinterpret_cast<const s4v*>(&feat_l[row][16 + (lane >> 4) * 4]);
                ah = __builtin_shufflevector(h0, h1, 0, 1, 2, 3, 4, 5, 6, 7);
                al = __builtin_shufflevector(l0, l1, 0, 1, 2, 3, 4, 5, 6, 7);
            }
            #pragma unroll
            for (int ctl = 0; ctl < 2; ++ctl) {
                f4v acc = {0.f, 0.f, 0.f, 0.f};
                acc = __builtin_amdgcn_mfma_f32_16x16x32_bf16(al, bh1[ctl], acc, 0, 0, 0);
                acc = __builtin_amdgcn_mfma_f32_16x16x32_bf16(ah, bl1[ctl], acc, 0, 0, 0);
                acc = __builtin_amdgcn_mfma_f32_16x16x32_bf16(ah, bh1[ctl], acc, 0, 0, 0);
                #pragma unroll
                for (int r = 0; r < 4; ++r) {
                    const float x = fmaxf(acc[r], 0.f);
                    xc[rt][ctl][r] = x;
                    v[rt * 4 + r] = fmaf(x, akv[ctl], v[rt * 4 + r]);
                }
            }
        }

        // logit reduce-scatter within each 16-lane group (15 shfl vs 64):
        // after stage k, lane-bit k-1 selects index-bit (4-k); final lane l
        // holds the group total for index bitrev4(l&15).
        {
            #pragma unroll
            for (int j = 0; j < 8; ++j) {
                const float send = (lane & 1) ? v[j] : v[j + 8];
                const float keep = (lane & 1) ? v[j + 8] : v[j];
                v[j] = keep + __shfl_xor(send, 1, 64);
            }
            #pragma unroll
            for (int j = 0; j < 4; ++j) {
                const float send = (lane & 2) ? v[j] : v[j + 4];
                const float keep = (lane & 2) ? v[j + 4] : v[j];
                v[j] = keep + __shfl_xor(send, 2, 64);
            }
            #pragma unroll
            for (int j = 0; j < 2; ++j) {
                const float send = (lane & 4) ? v[j] : v[j + 2];
                const float keep = (lane & 4) ? v[j + 2] : v[j];
                v[j] = keep + __shfl_xor(send, 4, 64);
            }
            {
                const float send = (lane & 8) ? v[0] : v[1];
                const float keep = (lane & 8) ? v[1] : v[0];
                v[0] = keep + __shfl_xor(send, 8, 64);
            }
        }
        __syncthreads();   // feat dead; part overlays feat
        {
            const int li  = lane & 15;
            const int idx = ((li & 1) << 3) | ((li & 2) << 1) | ((li & 4) >> 1) | ((li & 8) >> 3);
            const int rt  = idx >> 2, r = idx & 3;
            part[w][rt * 16 + bi_r[r]] = v[0];
        }
        __syncthreads();

        // softmax over t within each item
        if (tid < 64) {
            const float l = part[0][tid] + part[1][tid] + part[2][tid] + part[3][tid];
            float m1 = fmaxf(l, __shfl_xor(l, 1, 64));
            m1 = fmaxf(m1, __shfl_xor(m1, 2, 64));
            const float e = __expf(l - m1);
            float s = e + __shfl_xor(e, 1, 64);
            s += __shfl_xor(s, 2, 64);
            attnl[tid] = e * __builtin_amdgcn_rcpf(s);
        }
        __syncthreads();

        // pooling: thread-local
        #pragma unroll
        for (int rt = 0; rt < 4; ++rt) {
            float p0 = 0.f, p1 = 0.f;
            #pragma unroll
            for (int r = 0; r < 4; ++r) {
                const float a = attnl[rt * 16 + bi_r[r]];
                p0 = fmaf(a, xc[rt][0][r], p0);
                p1 = fmaf(a, xc[rt][1][r], p1);
            }
            const int item = rt * 4 + ib;
            const int c0 = w * 32 + hx0, c1 = c0 + 16;
            const unsigned short h0 = f2bf(p0), h1 = f2bf(p1);
            lpool_h[item][c0] = h0;  lpool_l[item][c0] = f2bf(p0 - bf2f(h0));
            lpool_h[item][c1] = h1;  lpool_l[item][c1] = f2bf(p1 - bf2f(h1));
        }
        __syncthreads();

        // phase 2: pooled(16x128) @ W_dense(128x256), full hi/lo (3 MFMA/frag)
        const s8v* Bh = reinterpret_cast<const s8v*>(wb + (variant == 1 ? 65536 : 0));
        const s8v* Bl = reinterpret_cast<const s8v*>(wb + (variant == 1 ? 98304 : 32768));
        f4v acc2[4] = {f4v{0,0,0,0}, f4v{0,0,0,0}, f4v{0,0,0,0}, f4v{0,0,0,0}};
        #pragma unroll
        for (int ks = 0; ks < 4; ++ks) {
            s8v ah, al;
            if (variant != 2) {
                ah = *reinterpret_cast<const s8v*>(&lpool_h[lane & 15][ks * 32 + (lane >> 4) * 8]);
                al = *reinterpret_cast<const s8v*>(&lpool_l[lane & 15][ks * 32 + (lane >> 4) * 8]);
            } else {
                const s4v h0 = *reinterpret_cast<const s4v*>(&lpool_h[lane & 15][ks * 32 + (lane >> 4) * 4]);
                const s4v h1 = *reinterpret_cast<const s4v*>(&lpool_h[lane & 15][ks * 32 + 16 + (lane >> 4) * 4]);
                const s4v l0 = *reinterpret_cast<const s4v*>(&lpool_l[lane & 15][ks * 32 + (lane >> 4) * 4]);
                const s4v l1 = *reinterpret_cast<const s4v*>(&lpool_l[lane & 15][ks * 32 + 16 + (lane >> 4) * 4]);
                ah = __builtin_shufflevector(h0, h1, 0, 1, 2, 3, 4, 5, 6, 7);
                al = __builtin_shufflevector(l0, l1, 0, 1, 2, 3, 4, 5, 6, 7);
            }
            #pragma unroll
            for (int nt = 0; nt < 4; ++nt) {
                const int idx = (ks * 16 + w * 4 + nt) * 64 + lane;
                const s8v bh = Bh[idx], bl = Bl[idx];
                acc2[nt] = __builtin_amdgcn_mfma_f32_16x16x32_bf16(al, bh, acc2[nt], 0, 0, 0);
                acc2[nt] = __builtin_amdgcn_mfma_f32_16x16x32_bf16(ah, bl, acc2[nt], 0, 0, 0);
                acc2[nt] = __builtin_amdgcn_mfma_f32_16x16x32_bf16(ah, bh, acc2[nt], 0, 0, 0);
            }
        }
        #pragma unroll
        for (int nt = 0; nt < 4; ++nt) {
            #pragma unroll
            for (int r = 0; r < 4; ++r) {
                const int h = w * 64 + nt * 16 + hx_r[r];
                out[(size_t)(b0 + bi_r[r]) * HID + h] = ftanh(acc2[nt][r] + b_dense[h]);
            }
        }
    } else {
        // ================= SAFE PATH (fp32; correctness-only) =================
        #pragma unroll 1
        for (int p = 0; p < 4; ++p) {
            const int item = w * 4 + p;
            float xc2[2][4], pt[4] = {0.f, 0.f, 0.f, 0.f};
            #pragma unroll 1
            for (int ch = 0; ch < 2; ++ch) {
                const int cc = lane + ch * 64;
                #pragma unroll
                for (int t = 0; t < 4; ++t) {
                    const int row = item * 4 + t;
                    float vv = 0.f;
                    #pragma unroll 5
                    for (int k = 0; k < 25; ++k) {
                        const float fv = bf2f(feat_h[row][k]) + bf2f(feat_l[row][k]);
                        vv = fmaf(fv, wbig_val(k, cc, W_fgn, b_fgn, W_root, b_conv), vv);
                    }
                    xc2[ch][t] = fmaxf(vv, 0.f);
                    pt[t] = fmaf(xc2[ch][t], attn_k[cc], pt[t]);
                }
            }
            #pragma unroll
            for (int st = 1; st < 64; st <<= 1) {
                #pragma unroll
                for (int t = 0; t < 4; ++t) pt[t] += __shfl_xor(pt[t], st, 64);
            }
            const float mx = fmaxf(fmaxf(pt[0], pt[1]), fmaxf(pt[2], pt[3]));
            const float e0 = __expf(pt[0] - mx), e1 = __expf(pt[1] - mx);
            const float e2 = __expf(pt[2] - mx), e3 = __expf(pt[3] - mx);
            const float inv = 1.f / (e0 + e1 + e2 + e3);
            poolf[item][lane]      = (e0 * xc2[0][0] + e1 * xc2[0][1] + e2 * xc2[0][2] + e3 * xc2[0][3]) * inv;
            poolf[item][lane + 64] = (e0 * xc2[1][0] + e1 * xc2[1][1] + e2 * xc2[1][2] + e3 * xc2[1][3]) * inv;
        }
        __syncthreads();

        const int col0 = w * 64 + (lane & 15) * 4;
        const int rb   = (lane >> 4) * 4;
        float acc[4][4];
        #pragma unroll
        for (int j = 0; j < 4; ++j)
            #pragma unroll
            for (int i = 0; i < 4; ++i) acc[j][i] = 0.f;
        #pragma unroll 4
        for (int cc = 0; cc < CH; cc += 4) {
            float4 pv[4], wr[4];
            #pragma unroll
            for (int j = 0; j < 4; ++j) {
                pv[j].x = poolf[rb + j][cc];     pv[j].y = poolf[rb + j][cc + 1];
                pv[j].z = poolf[rb + j][cc + 2]; pv[j].w = poolf[rb + j][cc + 3];
            }
            #pragma unroll
            for (int k = 0; k < 4; ++k)
                wr[k] = *reinterpret_cast<const float4*>(&W_dense[(size_t)(cc + k) * HID + col0]);
            #pragma unroll
            for (int j = 0; j < 4; ++j) {
                const float pj[4] = {pv[j].x, pv[j].y, pv[j].z, pv[j].w};
                #pragma unroll
                for (int k = 0; k < 4; ++k) {
                    acc[j][0] = fmaf(pj[k], wr[k].x, acc[j][0]);
                    acc[j][1] = fmaf(pj[k], wr[k].y, acc[j][1]);
                    acc[j][2] = fmaf(pj[k], wr[k].z, acc[j][2]);
                    acc[j][3] = fmaf(pj[k], wr[k].w, acc[j][3]);
                }
            }
        }
        const float4 bd = *reinterpret_cast<const float4*>(&b_dense[col0]);
        #pragma unroll
        for (int j = 0; j < 4; ++j) {
            float4 o;
            o.x = ftanh(acc[j][0] + bd.x);
            o.y = ftanh(acc[j][1] + bd.y);
            o.z = ftanh(acc[j][2] + bd.z);
            o.w = ftanh(acc[j][3] + bd.w);
            *reinterpret_cast<float4*>(&out[(size_t)(b0 + rb + j) * HID + col0]) = o;
        }
    }
}

extern "C" void kernel_launch(void* const* d_in, const int* in_sizes, int n_in,
                              void* d_out, int out_size, void* d_ws, size_t ws_size,
                              hipStream_t stream) {
    const float* obs     = (const float*)d_in[0];
    const float* W_fgn   = (const float*)d_in[1];
    const float* b_fgn   = (const float*)d_in[2];
    const float* W_root  = (const float*)d_in[3];
    const float* b_conv  = (const float*)d_in[4];
    const float* attn_k  = (const float*)d_in[5];
    const float* W_dense = (const float*)d_in[6];
    const float* b_dense = (const float*)d_in[7];
    float* out = (float*)d_out;

    const int Bn = in_sizes[0] / OBS_DIM;     // 16384
    const bool use_ws = (ws_size >= 320 * 1024) && (d_ws != nullptr);

    if (use_ws) {
        unsigned short* wb = (unsigned short*)d_ws;
        prepack<<<36, 256, 0, stream>>>(W_dense, W_fgn, b_fgn, W_root, b_conv, wb);
        gnn_main<<<Bn / BPB, 256, 0, stream>>>(obs, W_fgn, b_fgn, W_root, b_conv,
                                               attn_k, W_dense, wb,
                                               (const int*)(wb + 147456), b_dense, out);
    } else {
        gnn_main<<<Bn / BPB, 256, 0, stream>>>(obs, W_fgn, b_fgn, W_root, b_conv,
                                               attn_k, W_dense, nullptr, nullptr,
                                               b_dense, out);
    }
}